// Round 1
// baseline (3009.037 us; speedup 1.0000x reference)
//
#include <hip/hip_runtime.h>
#include <hip/hip_bf16.h>
#include <stdint.h>

#define IGNORE_INDEX (-100)

constexpr int kB2 = 8, kT = 1024, kH = 2048, kV = 32000;
constexpr int kM = kB2 * kT;          // 8192 token rows
constexpr int BM = 128, BN = 128, BK = 64;
constexpr int NSPLIT = 25;            // vocab splits
constexpr int VSLICE = kV / NSPLIT;   // 1280 cols per split
constexpr int NTILES = VSLICE / BN;   // 10 tiles per split
constexpr int MBLKS  = kM / BM;       // 64 row blocks
constexpr int KSTEPS = kH / BK;       // 32 K-steps

typedef __bf16 bf16_t;
typedef __bf16 bf16x8 __attribute__((ext_vector_type(8)));
typedef float  f32x4  __attribute__((ext_vector_type(4)));

// ---------------- cast fp32 -> bf16 (vectorized) ----------------
__global__ void cast_to_bf16(const float* __restrict__ src, uint2* __restrict__ dst, int n4) {
  int idx = blockIdx.x * blockDim.x + threadIdx.x;
  int stride = gridDim.x * blockDim.x;
  const float4* s = (const float4*)src;
  for (int i = idx; i < n4; i += stride) {
    float4 v = s[i];
    union { bf16_t h[4]; uint2 u; } p;
    p.h[0] = (bf16_t)v.x; p.h[1] = (bf16_t)v.y;
    p.h[2] = (bf16_t)v.z; p.h[3] = (bf16_t)v.w;
    dst[i] = p.u;
  }
}

// ---------------- fused GEMM + online logsumexp + target grab ----------------
// grid: NSPLIT * MBLKS blocks of 256 threads (4 waves).
// wave w owns rows [w*32, w*32+32) of the 128-row block, all 128 cols of each tile.
// D-frag mapping (16x16x32 bf16): col = lane&15, row = (lane>>4)*4 + reg.
__global__ __launch_bounds__(256) void fused_lse(
    const bf16_t* __restrict__ Wb,   // [V][H] bf16
    const bf16_t* __restrict__ Ab,   // [M][H] bf16
    const float* __restrict__ bias,  // [V]
    const int* __restrict__ target,  // [M]
    float* __restrict__ partials)    // [NSPLIT][M][4] : m, s, tgt_logit
{
  const int split = blockIdx.x / MBLKS;
  const int mblk  = blockIdx.x % MBLKS;
  const int tid  = threadIdx.x;
  const int lane = tid & 63;
  const int w    = tid >> 6;
  const int g    = lane >> 4;   // 16-lane group = one D row-group
  const int li   = lane & 15;   // column within frag
  const int rowbase = mblk * BM;

  __shared__ uint8_t Asm[BM * BK * 2];  // 16 KB
  __shared__ uint8_t Bsm[BN * BK * 2];  // 16 KB

  f32x4 acc[2][8];
  float rM[2][4], rS[2][4], rT[2][4];
  int   tg[2][4];
  const f32x4 vzero = {0.f, 0.f, 0.f, 0.f};

#pragma unroll
  for (int fr = 0; fr < 2; ++fr)
#pragma unroll
    for (int i = 0; i < 4; ++i) {
      rM[fr][i] = -1e30f; rS[fr][i] = 0.f; rT[fr][i] = 0.f;
      int trow = rowbase + w * 32 + fr * 16 + g * 4 + i;
      int t = target[trow];
      tg[fr][i] = (t == IGNORE_INDEX) ? 0 : t;   // labels = where(mask, target, 0)
    }

  const uint8_t* Agp = (const uint8_t*)(Ab + (size_t)rowbase * kH);

  for (int nt = 0; nt < NTILES; ++nt) {
    const int n0 = split * VSLICE + nt * BN;
    const uint8_t* Bgp = (const uint8_t*)(Wb + (size_t)n0 * kH);

#pragma unroll
    for (int fr = 0; fr < 2; ++fr)
#pragma unroll
      for (int cf = 0; cf < 8; ++cf)
        acc[fr][cf] = vzero;

    for (int kt = 0; kt < KSTEPS; ++kt) {
      const int k0 = kt * BK;
      __syncthreads();  // previous compute (or tile) done reading LDS
      // stage A,B tiles: 1024 16B chunks each; XOR-swizzle LDS column to kill
      // the 16-way bank conflict of a 128B-row layout (T2 recipe).
#pragma unroll
      for (int it = 0; it < 4; ++it) {
        int c   = tid + 256 * it;
        int row = c >> 3, c16 = c & 7;
        int loff = row * 128 + ((c16 ^ (row & 7)) << 4);
        size_t goff = (size_t)row * (kH * 2) + (size_t)(k0 * 2) + c16 * 16;
        *(int4*)(Asm + loff) = *(const int4*)(Agp + goff);
        *(int4*)(Bsm + loff) = *(const int4*)(Bgp + goff);
      }
      __syncthreads();
      // compute: 2 k-slices of 32, 2x8 frags -> 32 MFMA / wave / K-step
#pragma unroll
      for (int ks = 0; ks < 2; ++ks) {
        bf16x8 af[2];
#pragma unroll
        for (int fr = 0; fr < 2; ++fr) {
          int row = w * 32 + fr * 16 + li;
          int c16 = ks * 4 + g;
          af[fr] = *(const bf16x8*)(Asm + row * 128 + ((c16 ^ (row & 7)) << 4));
        }
#pragma unroll
        for (int cf = 0; cf < 8; ++cf) {
          int row = cf * 16 + li;
          int c16 = ks * 4 + g;
          bf16x8 bfv = *(const bf16x8*)(Bsm + row * 128 + ((c16 ^ (row & 7)) << 4));
          acc[0][cf] = __builtin_amdgcn_mfma_f32_16x16x32_bf16(af[0], bfv, acc[0][cf], 0, 0, 0);
          acc[1][cf] = __builtin_amdgcn_mfma_f32_16x16x32_bf16(af[1], bfv, acc[1][cf], 0, 0, 0);
        }
      }
    }

    // ---- epilogue for this N-tile (registers only; no barrier needed) ----
    float bv[8];
#pragma unroll
    for (int cf = 0; cf < 8; ++cf) bv[cf] = bias[n0 + cf * 16 + li];
#pragma unroll
    for (int fr = 0; fr < 2; ++fr)
#pragma unroll
      for (int cf = 0; cf < 8; ++cf)
#pragma unroll
        for (int i = 0; i < 4; ++i)
          acc[fr][cf][i] += bv[cf];

#pragma unroll
    for (int fr = 0; fr < 2; ++fr)
#pragma unroll
      for (int i = 0; i < 4; ++i) {
        // tile row-max over 128 cols: 8 frags per lane, then 16-lane group reduce
        float tmax = acc[fr][0][i];
#pragma unroll
        for (int cf = 1; cf < 8; ++cf) tmax = fmaxf(tmax, acc[fr][cf][i]);
#pragma unroll
        for (int d = 1; d <= 8; d <<= 1) tmax = fmaxf(tmax, __shfl_xor(tmax, d));
        float tsum = 0.f;
#pragma unroll
        for (int cf = 0; cf < 8; ++cf) tsum += __expf(acc[fr][cf][i] - tmax);
#pragma unroll
        for (int d = 1; d <= 8; d <<= 1) tsum += __shfl_xor(tsum, d);
        // online update (rM=-1e30 start: exp(-huge)=0, no NaN)
        float nm = fmaxf(rM[fr][i], tmax);
        rS[fr][i] = rS[fr][i] * __expf(rM[fr][i] - nm) + tsum * __expf(tmax - nm);
        rM[fr][i] = nm;
        // target-logit grab (c uniform within the 16-lane group; static cf index)
        int c = tg[fr][i] - n0;
#pragma unroll
        for (int cf = 0; cf < 8; ++cf)
          rT[fr][i] += ((c >> 4) == cf && (c & 15) == li) ? acc[fr][cf][i] : 0.f;
      }
  }

  // final: reduce target partials across the 16-lane group, write per-row partials
#pragma unroll
  for (int fr = 0; fr < 2; ++fr)
#pragma unroll
    for (int i = 0; i < 4; ++i) {
#pragma unroll
      for (int d = 1; d <= 8; d <<= 1) rT[fr][i] += __shfl_xor(rT[fr][i], d);
      if (li == 0) {
        int row = rowbase + w * 32 + fr * 16 + g * 4 + i;
        float* p = partials + ((size_t)split * kM + row) * 4;
        p[0] = rM[fr][i]; p[1] = rS[fr][i]; p[2] = rT[fr][i];
      }
    }
}

// ---------------- combine split partials -> per-token logp ----------------
__global__ void combine_lse(const float* __restrict__ partials, float* __restrict__ per_tok) {
  int row = blockIdx.x * blockDim.x + threadIdx.x;
  if (row >= kM) return;
  float m = -1e30f, s = 0.f, t = 0.f;
  for (int sp = 0; sp < NSPLIT; ++sp) {
    const float* p = partials + ((size_t)sp * kM + row) * 4;
    float mi = p[0], si = p[1];
    t += p[2];
    if (mi > m) { s = s * __expf(m - mi) + si; m = mi; }
    else        { s += si * __expf(mi - m); }
  }
  per_tok[row] = t - (m + logf(s));
}

// ---------------- final scalar loss ----------------
__global__ __launch_bounds__(1024) void final_loss(
    const float* __restrict__ per_tok, const int* __restrict__ target, float* __restrict__ out)
{
  __shared__ float redv[16], redc[16];
  __shared__ float ssum[8], scnt[8];
  int t = threadIdx.x;
  int wid = t >> 6, lane = t & 63;
  for (int b = 0; b < 8; ++b) {
    int row = b * 1024 + t;
    float mk = (target[row] != IGNORE_INDEX) ? 1.f : 0.f;
    float v = per_tok[row] * mk;
#pragma unroll
    for (int d = 1; d <= 32; d <<= 1) { v += __shfl_xor(v, d); mk += __shfl_xor(mk, d); }
    if (lane == 0) { redv[wid] = v; redc[wid] = mk; }
    __syncthreads();
    if (t == 0) {
      float sv = 0.f, sc = 0.f;
      for (int j = 0; j < 16; ++j) { sv += redv[j]; sc += redc[j]; }
      ssum[b] = sv; scnt[b] = sc;
    }
    __syncthreads();
  }
  if (t == 0) {
    float nsum = 0.f, ncnt = 0.f;
    for (int b = 0; b < 4; ++b) { nsum += ssum[b]; ncnt += scnt[b]; }
    float nll = -nsum / ncnt;
    float pref = 0.f;
    for (int b = 0; b < 4; ++b) {
      float avc = ssum[b] / scnt[b];
      float avr = ssum[b + 4] / scnt[b + 4];
      float d = 0.1f * (avc - avr);                 // BETA = 0.1
      float ls = (d >= 0.f) ? -log1pf(__expf(-d)) : d - log1pf(__expf(d));
      pref += ls;
    }
    pref *= 0.25f;                                  // mean over 4 pairs
    out[0] = 1.0f * nll - pref;                     // ALPHA = 1.0
  }
}

extern "C" void kernel_launch(void* const* d_in, const int* in_sizes, int n_in,
                              void* d_out, int out_size, void* d_ws, size_t ws_size,
                              hipStream_t stream) {
  const float* lin_weight = (const float*)d_in[0];  // [V][H]
  const float* input      = (const float*)d_in[1];  // [B2][T][H]
  const int*   target     = (const int*)d_in[2];    // [B2][T]
  const float* bias       = (const float*)d_in[3];  // [V]
  float* out = (float*)d_out;

  uint8_t* ws = (uint8_t*)d_ws;
  size_t offW = 0;
  size_t offA = offW + (size_t)kV * kH * 2;            // 131,072,000 B
  size_t offP = offA + (size_t)kM * kH * 2;            // +33,554,432 B
  size_t offT = offP + (size_t)NSPLIT * kM * 4 * 4;    // +3,276,800 B
  size_t need = offT + (size_t)kM * 4;
  if (ws_size < need) return;  // clean failure signal (output stays 0)

  bf16_t* Wb = (bf16_t*)(ws + offW);
  bf16_t* Ab = (bf16_t*)(ws + offA);
  float* partials = (float*)(ws + offP);
  float* per_tok  = (float*)(ws + offT);

  cast_to_bf16<<<2048, 256, 0, stream>>>(lin_weight, (uint2*)Wb, kV * kH / 4);
  cast_to_bf16<<<1024, 256, 0, stream>>>(input, (uint2*)Ab, kM * kH / 4);
  fused_lse<<<NSPLIT * MBLKS, 256, 0, stream>>>(Wb, Ab, bias, target, partials);
  combine_lse<<<kM / 256, 256, 0, stream>>>(partials, per_tok);
  final_loss<<<1, 1024, 0, stream>>>(per_tok, target, out);
}

// Round 3
// 3003.287 us; speedup vs baseline: 1.0019x; 1.0019x over previous
//
#include <hip/hip_runtime.h>
#include <hip/hip_bf16.h>
#include <stdint.h>

#define IGNORE_INDEX (-100)

constexpr int kB2 = 8, kT = 1024, kH = 2048, kV = 32000;
constexpr int kM = kB2 * kT;          // 8192 token rows
constexpr int BM = 128, BN = 128, BK = 64;
constexpr int MBLKS  = kM / BM;       // 64 row blocks
constexpr int KSTEPS = kH / BK;       // 32 K-steps

typedef __bf16 bf16_t;
typedef __bf16 bf16x8 __attribute__((ext_vector_type(8)));
typedef float  f32x4  __attribute__((ext_vector_type(4)));

// ---------------- cast fp32 -> bf16 (vectorized) ----------------
__global__ void cast_to_bf16(const float* __restrict__ src, uint2* __restrict__ dst, int n4) {
  int idx = blockIdx.x * blockDim.x + threadIdx.x;
  int stride = gridDim.x * blockDim.x;
  const float4* s = (const float4*)src;
  for (int i = idx; i < n4; i += stride) {
    float4 v = s[i];
    union { bf16_t h[4]; uint2 u; } p;
    p.h[0] = (bf16_t)v.x; p.h[1] = (bf16_t)v.y;
    p.h[2] = (bf16_t)v.z; p.h[3] = (bf16_t)v.w;
    dst[i] = p.u;
  }
}

// async global->LDS, 16B per lane. LDS dest is wave-uniform base + lane*16.
__device__ __forceinline__ void gload_lds16(const void* g, void* l) {
  __builtin_amdgcn_global_load_lds(
      (const __attribute__((address_space(1))) void*)g,
      (__attribute__((address_space(3))) void*)l, 16, 0, 0);
}

// ---------------- fused GEMM + online logsumexp + target grab ----------------
// grid: nsplit * MBLKS blocks of 256 threads (4 waves), XCD-swizzled.
// wave w owns rows [w*32, w*32+32) of the 128-row block, all 128 cols of each tile.
// D-frag mapping (16x16x32 bf16): col = lane&15, row = (lane>>4)*4 + reg.
// LDS layout: linear [row][8 chunks of 16B]; content of chunk (row,j) is global
// chunk (row, j ^ (row&7)) — staged by pre-swizzling the per-lane GLOBAL source
// (global_load_lds writes linearly), consumed by XOR-swizzled ds_read (rule #21).
__global__ __launch_bounds__(256) void fused_lse(
    const bf16_t* __restrict__ Wb,   // [V][H] bf16
    const bf16_t* __restrict__ Ab,   // [M][H] bf16
    const float* __restrict__ bias,  // [V]
    const int* __restrict__ target,  // [M]
    float4* __restrict__ partials,   // [nsplit][M] : (m, s, tgt_logit, 0)
    int ntiles)                      // N-tiles of 128 per split
{
  const int nwg = gridDim.x;
  const int swz = (blockIdx.x & 7) * (nwg >> 3) + (blockIdx.x >> 3);  // bijective (nwg%8==0)
  const int split = swz / MBLKS;
  const int mblk  = swz % MBLKS;
  const int tid  = threadIdx.x;
  const int lane = tid & 63;
  const int w    = tid >> 6;
  const int g    = lane >> 4;   // 16-lane group = one D row-group
  const int li   = lane & 15;   // column within frag
  const int rowbase = mblk * BM;
  const int vslice = ntiles * BN;

  __shared__ __align__(16) uint8_t Asm[BM * BK * 2];  // 16 KB
  __shared__ __align__(16) uint8_t Bsm[BN * BK * 2];  // 16 KB

  f32x4 acc[2][8];
  float rM[2][4], rS[2][4], rT[2][4];
  int   tg[2][4];
  const f32x4 vzero = {0.f, 0.f, 0.f, 0.f};

#pragma unroll
  for (int fr = 0; fr < 2; ++fr)
#pragma unroll
    for (int i = 0; i < 4; ++i) {
      rM[fr][i] = -1e30f; rS[fr][i] = 0.f; rT[fr][i] = 0.f;
      int trow = rowbase + w * 32 + fr * 16 + g * 4 + i;
      int t = target[trow];
      tg[fr][i] = (t == IGNORE_INDEX) ? 0 : t;   // labels = where(mask, target, 0)
    }

  // per-lane staging geometry: this wave stages LDS segments [w*4, w*4+4)
  // (1 KB each). chunk c = seg*64 + lane; row = c>>3, col = c&7; global source
  // column is col ^ (row&7) (involution => LDS content matches read swizzle).
  const uint8_t* Agp = (const uint8_t*)(Ab + (size_t)rowbase * kH);

  for (int nt = 0; nt < ntiles; ++nt) {
    const int n0 = split * vslice + nt * BN;
    const uint8_t* Bgp = (const uint8_t*)(Wb + (size_t)n0 * kH);

#pragma unroll
    for (int fr = 0; fr < 2; ++fr)
#pragma unroll
      for (int cf = 0; cf < 8; ++cf)
        acc[fr][cf] = vzero;

    for (int kt = 0; kt < KSTEPS; ++kt) {
      const int k0 = kt * BK;
      __syncthreads();  // all waves done reading previous tile's LDS
#pragma unroll
      for (int it = 0; it < 4; ++it) {
        int seg = w * 4 + it;
        int c   = seg * 64 + lane;
        int row = c >> 3, col = c & 7;
        size_t goff = (size_t)row * (kH * 2) + (size_t)(k0 * 2) + ((col ^ (row & 7)) << 4);
        gload_lds16(Agp + goff, Asm + seg * 1024);
        gload_lds16(Bgp + goff, Bsm + seg * 1024);
      }
      __syncthreads();  // compiler drains vmcnt(0) before barrier -> tiles ready
      // compute: 2 k-slices of 32, 2x8 frags -> 32 MFMA / wave / K-step
#pragma unroll
      for (int ks = 0; ks < 2; ++ks) {
        bf16x8 af[2];
#pragma unroll
        for (int fr = 0; fr < 2; ++fr) {
          int row = w * 32 + fr * 16 + li;
          int c16 = ks * 4 + g;
          af[fr] = *(const bf16x8*)(Asm + row * 128 + ((c16 ^ (row & 7)) << 4));
        }
#pragma unroll
        for (int cf = 0; cf < 8; ++cf) {
          int row = cf * 16 + li;
          int c16 = ks * 4 + g;
          bf16x8 bfv = *(const bf16x8*)(Bsm + row * 128 + ((c16 ^ (row & 7)) << 4));
          acc[0][cf] = __builtin_amdgcn_mfma_f32_16x16x32_bf16(af[0], bfv, acc[0][cf], 0, 0, 0);
          acc[1][cf] = __builtin_amdgcn_mfma_f32_16x16x32_bf16(af[1], bfv, acc[1][cf], 0, 0, 0);
        }
      }
    }

    // ---- epilogue for this N-tile (registers only; no barrier needed) ----
    float bv[8];
#pragma unroll
    for (int cf = 0; cf < 8; ++cf) bv[cf] = bias[n0 + cf * 16 + li];
#pragma unroll
    for (int fr = 0; fr < 2; ++fr)
#pragma unroll
      for (int cf = 0; cf < 8; ++cf)
#pragma unroll
        for (int i = 0; i < 4; ++i)
          acc[fr][cf][i] += bv[cf];

#pragma unroll
    for (int fr = 0; fr < 2; ++fr)
#pragma unroll
      for (int i = 0; i < 4; ++i) {
        // tile row-max over 128 cols: 8 frags per lane, then 16-lane group reduce
        float tmax = acc[fr][0][i];
#pragma unroll
        for (int cf = 1; cf < 8; ++cf) tmax = fmaxf(tmax, acc[fr][cf][i]);
#pragma unroll
        for (int d = 1; d <= 8; d <<= 1) tmax = fmaxf(tmax, __shfl_xor(tmax, d));
        float tsum = 0.f;
#pragma unroll
        for (int cf = 0; cf < 8; ++cf) tsum += __expf(acc[fr][cf][i] - tmax);
#pragma unroll
        for (int d = 1; d <= 8; d <<= 1) tsum += __shfl_xor(tsum, d);
        // online update (rM=-1e30 start: exp(-huge)=0, no NaN)
        float nm = fmaxf(rM[fr][i], tmax);
        rS[fr][i] = rS[fr][i] * __expf(rM[fr][i] - nm) + tsum * __expf(tmax - nm);
        rM[fr][i] = nm;
        // target-logit grab (c uniform within the 16-lane group; static cf index)
        int c = tg[fr][i] - n0;
#pragma unroll
        for (int cf = 0; cf < 8; ++cf)
          rT[fr][i] += ((c >> 4) == cf && (c & 15) == li) ? acc[fr][cf][i] : 0.f;
      }
  }

  // final: reduce target partials across the 16-lane group, write per-row partials
#pragma unroll
  for (int fr = 0; fr < 2; ++fr)
#pragma unroll
    for (int i = 0; i < 4; ++i) {
#pragma unroll
      for (int d = 1; d <= 8; d <<= 1) rT[fr][i] += __shfl_xor(rT[fr][i], d);
      if (li == 0) {
        int row = rowbase + w * 32 + fr * 16 + g * 4 + i;
        partials[(size_t)split * kM + row] = float4{rM[fr][i], rS[fr][i], rT[fr][i], 0.f};
      }
    }
}

// ---------------- combine split partials -> per-token logp ----------------
// one wave per row; 64 lanes strided over splits, shfl LSE-merge.
// grid must be kM/4 blocks (4 waves per block, one row per wave).
__global__ __launch_bounds__(256) void combine_lse(
    const float4* __restrict__ partials, float* __restrict__ per_tok, int nsplit)
{
  int row  = blockIdx.x * 4 + (threadIdx.x >> 6);
  int lane = threadIdx.x & 63;
  float m = -1e30f, s = 0.f, t = 0.f;
  for (int sp = lane; sp < nsplit; sp += 64) {
    float4 p = partials[(size_t)sp * kM + row];
    t += p.z;
    float nm = fmaxf(m, p.x);
    s = s * __expf(m - nm) + p.y * __expf(p.x - nm);
    m = nm;
  }
#pragma unroll
  for (int d = 1; d < 64; d <<= 1) {
    float mo = __shfl_xor(m, d), so = __shfl_xor(s, d), to = __shfl_xor(t, d);
    float nm = fmaxf(m, mo);
    s = s * __expf(m - nm) + so * __expf(mo - nm);
    m = nm; t += to;
  }
  if (lane == 0) per_tok[row] = t - (m + logf(s));
}

// ---------------- final scalar loss ----------------
__global__ __launch_bounds__(1024) void final_loss(
    const float* __restrict__ per_tok, const int* __restrict__ target, float* __restrict__ out)
{
  __shared__ float redv[16], redc[16];
  __shared__ float ssum[8], scnt[8];
  int t = threadIdx.x;
  int wid = t >> 6, lane = t & 63;
  for (int b = 0; b < 8; ++b) {
    int row = b * 1024 + t;
    float mk = (target[row] != IGNORE_INDEX) ? 1.f : 0.f;
    float v = per_tok[row] * mk;
#pragma unroll
    for (int d = 1; d <= 32; d <<= 1) { v += __shfl_xor(v, d); mk += __shfl_xor(mk, d); }
    if (lane == 0) { redv[wid] = v; redc[wid] = mk; }
    __syncthreads();
    if (t == 0) {
      float sv = 0.f, sc = 0.f;
      for (int j = 0; j < 16; ++j) { sv += redv[j]; sc += redc[j]; }
      ssum[b] = sv; scnt[b] = sc;
    }
    __syncthreads();
  }
  if (t == 0) {
    float nsum = 0.f, ncnt = 0.f;
    for (int b = 0; b < 4; ++b) { nsum += ssum[b]; ncnt += scnt[b]; }
    float nll = -nsum / ncnt;
    float pref = 0.f;
    for (int b = 0; b < 4; ++b) {
      float avc = ssum[b] / scnt[b];
      float avr = ssum[b + 4] / scnt[b + 4];
      float d = 0.1f * (avc - avr);                 // BETA = 0.1
      float ls = (d >= 0.f) ? -log1pf(__expf(-d)) : d - log1pf(__expf(d));
      pref += ls;
    }
    pref *= 0.25f;                                  // mean over 4 pairs
    out[0] = 1.0f * nll - pref;                     // ALPHA = 1.0
  }
}

extern "C" void kernel_launch(void* const* d_in, const int* in_sizes, int n_in,
                              void* d_out, int out_size, void* d_ws, size_t ws_size,
                              hipStream_t stream) {
  const float* lin_weight = (const float*)d_in[0];  // [V][H]
  const float* input      = (const float*)d_in[1];  // [B2][T][H]
  const int*   target     = (const int*)d_in[2];    // [B2][T]
  const float* bias       = (const float*)d_in[3];  // [V]
  float* out = (float*)d_out;

  uint8_t* ws = (uint8_t*)d_ws;
  size_t offW = 0;
  size_t offA = offW + (size_t)kV * kH * 2;            // 131,072,000 B
  size_t offP = offA + (size_t)kM * kH * 2;            // +33,554,432 B

  // pick the finest vocab split whose partials fit the workspace
  // (round-1 proved nsplit=25 fits; prefer 125 => 8000 WGs, ~4% tail)
  const int cand[3] = {125, 50, 25};
  int nsplit = 0;
  for (int ci = 0; ci < 3; ++ci) {
    size_t need = offP + (size_t)cand[ci] * kM * 16 + (size_t)kM * 4;
    if (need <= ws_size) { nsplit = cand[ci]; break; }
  }
  if (nsplit == 0) return;  // clean failure signal (output stays 0)
  int ntiles = kV / (nsplit * BN);
  size_t offT = offP + (size_t)nsplit * kM * 16;

  bf16_t* Wb = (bf16_t*)(ws + offW);
  bf16_t* Ab = (bf16_t*)(ws + offA);
  float4* partials = (float4*)(ws + offP);
  float*  per_tok  = (float*)(ws + offT);

  cast_to_bf16<<<2048, 256, 0, stream>>>(lin_weight, (uint2*)Wb, kV * kH / 4);
  cast_to_bf16<<<1024, 256, 0, stream>>>(input, (uint2*)Ab, kM * kH / 4);
  fused_lse<<<nsplit * MBLKS, 256, 0, stream>>>(Wb, Ab, bias, target, partials, ntiles);
  combine_lse<<<kM / 4, 256, 0, stream>>>(partials, per_tok, nsplit);
  final_loss<<<1, 1024, 0, stream>>>(per_tok, target, out);
}

// Round 4
// 1687.148 us; speedup vs baseline: 1.7835x; 1.7801x over previous
//
#include <hip/hip_runtime.h>
#include <hip/hip_bf16.h>
#include <stdint.h>

#define IGNORE_INDEX (-100)

constexpr int kB2 = 8, kT = 1024, kH = 2048, kV = 32000;
constexpr int kM = kB2 * kT;          // 8192 token rows
constexpr int BM = 128, BN = 128, BK = 64;
constexpr int MBLKS  = kM / BM;       // 64 row blocks
constexpr int KSTEPS = kH / BK;       // 32 K-steps per N-tile

typedef __bf16 bf16_t;
typedef __bf16 bf16x8 __attribute__((ext_vector_type(8)));
typedef float  f32x4  __attribute__((ext_vector_type(4)));

// ---------------- cast fp32 -> bf16 (vectorized) ----------------
__global__ void cast_to_bf16(const float* __restrict__ src, uint2* __restrict__ dst, int n4) {
  int idx = blockIdx.x * blockDim.x + threadIdx.x;
  int stride = gridDim.x * blockDim.x;
  const float4* s = (const float4*)src;
  for (int i = idx; i < n4; i += stride) {
    float4 v = s[i];
    union { bf16_t h[4]; uint2 u; } p;
    p.h[0] = (bf16_t)v.x; p.h[1] = (bf16_t)v.y;
    p.h[2] = (bf16_t)v.z; p.h[3] = (bf16_t)v.w;
    dst[i] = p.u;
  }
}

// async global->LDS, 16B per lane. LDS dest is wave-uniform base + lane*16.
__device__ __forceinline__ void gload_lds16(const void* g, void* l) {
  __builtin_amdgcn_global_load_lds(
      (const __attribute__((address_space(1))) void*)g,
      (__attribute__((address_space(3))) void*)l, 16, 0, 0);
}

// ---------------- fused GEMM + online logsumexp + target grab ----------------
// 2-phase double-buffered pipeline (T3 minimum recipe):
//   barrier; STAGE(buf^1, s+1); compute(buf, s); [epilogue at N-tile end]; flip.
// One barrier per K-step; __syncthreads() drains vmcnt(0), so the next-step
// loads (issued BEFORE compute) pay only max(0, latency - compute).
// LDS layout per buffer: linear [row][8 chunks of 16B]; chunk (row,j) holds
// global chunk (row, j ^ (row&7)) — pre-swizzled global source, swizzled read
// (rule #21; involution).
__global__ __launch_bounds__(256, 2) void fused_lse(
    const bf16_t* __restrict__ Wb,   // [V][H] bf16
    const bf16_t* __restrict__ Ab,   // [M][H] bf16
    const float* __restrict__ bias,  // [V]
    const int* __restrict__ target,  // [M]
    float4* __restrict__ partials,   // [nsplit][M] : (m, s, tgt_logit, 0)
    int ntiles)                      // N-tiles of 128 per split
{
  const int nwg = gridDim.x;
  const int swz = (blockIdx.x & 7) * (nwg >> 3) + (blockIdx.x >> 3);  // bijective (nwg%8==0)
  const int split = swz / MBLKS;
  const int mblk  = swz % MBLKS;
  const int tid  = threadIdx.x;
  const int lane = tid & 63;
  const int w    = tid >> 6;
  const int g    = lane >> 4;   // 16-lane group = one D row-group
  const int li   = lane & 15;   // column within frag
  const int rowbase = mblk * BM;
  const int vslice = ntiles * BN;

  __shared__ __align__(16) uint8_t Asm[2][BM * BK * 2];  // 2 x 16 KB
  __shared__ __align__(16) uint8_t Bsm[2][BN * BK * 2];  // 2 x 16 KB

  f32x4 acc[2][8];
  float rM[2][4], rS[2][4], rT[2][4];
  int   tg[2][4];
  const f32x4 vzero = {0.f, 0.f, 0.f, 0.f};

#pragma unroll
  for (int fr = 0; fr < 2; ++fr)
#pragma unroll
    for (int i = 0; i < 4; ++i) {
      rM[fr][i] = -1e30f; rS[fr][i] = 0.f; rT[fr][i] = 0.f;
      int trow = rowbase + w * 32 + fr * 16 + g * 4 + i;
      int t = target[trow];
      tg[fr][i] = (t == IGNORE_INDEX) ? 0 : t;   // labels = where(mask, target, 0)
#pragma unroll
      for (int cf = 0; cf < 8; ++cf) { acc[0][cf] = vzero; acc[1][cf] = vzero; }
    }

  // per-thread staging geometry, hoisted: wave w stages LDS segments
  // [w*4, w*4+4) (1 KB each). chunk c = seg*64 + lane; row = c>>3, col = c&7;
  // global source column col ^ (row&7).
  int goff_it[4], loff_it[4];
#pragma unroll
  for (int it = 0; it < 4; ++it) {
    int seg = w * 4 + it;
    int c   = seg * 64 + lane;
    int row = c >> 3, col = c & 7;
    goff_it[it] = row * (kH * 2) + ((col ^ (row & 7)) << 4);
    loff_it[it] = seg * 1024;
  }

  const uint8_t* Agp = (const uint8_t*)(Ab + (size_t)rowbase * kH);
  const uint8_t* Wgp = (const uint8_t*)Wb + (size_t)split * vslice * (kH * 2);

  const int S = ntiles * KSTEPS;

  // ---- prologue: stage step 0 into buffer 0 ----
  {
    const uint8_t* Bgp = Wgp;  // nt=0, kt=0
#pragma unroll
    for (int it = 0; it < 4; ++it) {
      gload_lds16(Agp + goff_it[it], Asm[0] + loff_it[it]);
      gload_lds16(Bgp + goff_it[it], Bsm[0] + loff_it[it]);
    }
  }

  int cur = 0;
  for (int s = 0; s < S; ++s) {
    __syncthreads();  // drains vmcnt(0): buf[cur] staged; all reads of buf[cur^1] done

    // stage step s+1 into buf[cur^1] (loads fly under this step's compute)
    if (s + 1 < S) {
      int nt1 = (s + 1) >> 5, kb1 = ((s + 1) & 31) << 7;
      const uint8_t* Bgp = Wgp + (size_t)nt1 * BN * (kH * 2);
#pragma unroll
      for (int it = 0; it < 4; ++it) {
        gload_lds16(Agp + goff_it[it] + kb1, Asm[cur ^ 1] + loff_it[it]);
        gload_lds16(Bgp + goff_it[it] + kb1, Bsm[cur ^ 1] + loff_it[it]);
      }
    }

    // compute step s from buf[cur]: 2 k-slices of 32, 2x8 frags -> 32 MFMA/wave
    const uint8_t* As = Asm[cur];
    const uint8_t* Bs = Bsm[cur];
#pragma unroll
    for (int ks = 0; ks < 2; ++ks) {
      bf16x8 af[2];
#pragma unroll
      for (int fr = 0; fr < 2; ++fr) {
        int row = w * 32 + fr * 16 + li;
        int c16 = ks * 4 + g;
        af[fr] = *(const bf16x8*)(As + row * 128 + ((c16 ^ (row & 7)) << 4));
      }
#pragma unroll
      for (int cf = 0; cf < 8; ++cf) {
        int row = cf * 16 + li;
        int c16 = ks * 4 + g;
        bf16x8 bfv = *(const bf16x8*)(Bs + row * 128 + ((c16 ^ (row & 7)) << 4));
        acc[0][cf] = __builtin_amdgcn_mfma_f32_16x16x32_bf16(af[0], bfv, acc[0][cf], 0, 0, 0);
        acc[1][cf] = __builtin_amdgcn_mfma_f32_16x16x32_bf16(af[1], bfv, acc[1][cf], 0, 0, 0);
      }
    }

    // ---- N-tile epilogue (registers/shfl only; overlaps in-flight loads) ----
    if ((s & 31) == 31) {
      int n0 = split * vslice + (s >> 5) * BN;
      float bv[8];
#pragma unroll
      for (int cf = 0; cf < 8; ++cf) bv[cf] = bias[n0 + cf * 16 + li];
#pragma unroll
      for (int fr = 0; fr < 2; ++fr)
#pragma unroll
        for (int cf = 0; cf < 8; ++cf)
#pragma unroll
          for (int i = 0; i < 4; ++i)
            acc[fr][cf][i] += bv[cf];

#pragma unroll
      for (int fr = 0; fr < 2; ++fr)
#pragma unroll
        for (int i = 0; i < 4; ++i) {
          float tmax = acc[fr][0][i];
#pragma unroll
          for (int cf = 1; cf < 8; ++cf) tmax = fmaxf(tmax, acc[fr][cf][i]);
#pragma unroll
          for (int d = 1; d <= 8; d <<= 1) tmax = fmaxf(tmax, __shfl_xor(tmax, d));
          float tsum = 0.f;
#pragma unroll
          for (int cf = 0; cf < 8; ++cf) tsum += __expf(acc[fr][cf][i] - tmax);
#pragma unroll
          for (int d = 1; d <= 8; d <<= 1) tsum += __shfl_xor(tsum, d);
          float nm = fmaxf(rM[fr][i], tmax);
          rS[fr][i] = rS[fr][i] * __expf(rM[fr][i] - nm) + tsum * __expf(tmax - nm);
          rM[fr][i] = nm;
          int c = tg[fr][i] - n0;
#pragma unroll
          for (int cf = 0; cf < 8; ++cf)
            rT[fr][i] += ((c >> 4) == cf && (c & 15) == li) ? acc[fr][cf][i] : 0.f;
#pragma unroll
          for (int cf = 0; cf < 8; ++cf) acc[fr][cf][i] = 0.f;
        }
    }

    cur ^= 1;
  }

  // final: reduce target partials across the 16-lane group, write per-row partials
#pragma unroll
  for (int fr = 0; fr < 2; ++fr)
#pragma unroll
    for (int i = 0; i < 4; ++i) {
#pragma unroll
      for (int d = 1; d <= 8; d <<= 1) rT[fr][i] += __shfl_xor(rT[fr][i], d);
      if (li == 0) {
        int row = rowbase + w * 32 + fr * 16 + g * 4 + i;
        partials[(size_t)split * kM + row] = float4{rM[fr][i], rS[fr][i], rT[fr][i], 0.f};
      }
    }
}

// ---------------- combine split partials -> per-token logp ----------------
// one wave per row; 64 lanes strided over splits, shfl LSE-merge.
// grid must be kM/4 blocks (4 waves per block, one row per wave).
__global__ __launch_bounds__(256) void combine_lse(
    const float4* __restrict__ partials, float* __restrict__ per_tok, int nsplit)
{
  int row  = blockIdx.x * 4 + (threadIdx.x >> 6);
  int lane = threadIdx.x & 63;
  float m = -1e30f, s = 0.f, t = 0.f;
  for (int sp = lane; sp < nsplit; sp += 64) {
    float4 p = partials[(size_t)sp * kM + row];
    t += p.z;
    float nm = fmaxf(m, p.x);
    s = s * __expf(m - nm) + p.y * __expf(p.x - nm);
    m = nm;
  }
#pragma unroll
  for (int d = 1; d < 64; d <<= 1) {
    float mo = __shfl_xor(m, d), so = __shfl_xor(s, d), to = __shfl_xor(t, d);
    float nm = fmaxf(m, mo);
    s = s * __expf(m - nm) + so * __expf(mo - nm);
    m = nm; t += to;
  }
  if (lane == 0) per_tok[row] = t - (m + logf(s));
}

// ---------------- final scalar loss ----------------
__global__ __launch_bounds__(1024) void final_loss(
    const float* __restrict__ per_tok, const int* __restrict__ target, float* __restrict__ out)
{
  __shared__ float redv[16], redc[16];
  __shared__ float ssum[8], scnt[8];
  int t = threadIdx.x;
  int wid = t >> 6, lane = t & 63;
  for (int b = 0; b < 8; ++b) {
    int row = b * 1024 + t;
    float mk = (target[row] != IGNORE_INDEX) ? 1.f : 0.f;
    float v = per_tok[row] * mk;
#pragma unroll
    for (int d = 1; d <= 32; d <<= 1) { v += __shfl_xor(v, d); mk += __shfl_xor(mk, d); }
    if (lane == 0) { redv[wid] = v; redc[wid] = mk; }
    __syncthreads();
    if (t == 0) {
      float sv = 0.f, sc = 0.f;
      for (int j = 0; j < 16; ++j) { sv += redv[j]; sc += redc[j]; }
      ssum[b] = sv; scnt[b] = sc;
    }
    __syncthreads();
  }
  if (t == 0) {
    float nsum = 0.f, ncnt = 0.f;
    for (int b = 0; b < 4; ++b) { nsum += ssum[b]; ncnt += scnt[b]; }
    float nll = -nsum / ncnt;
    float pref = 0.f;
    for (int b = 0; b < 4; ++b) {
      float avc = ssum[b] / scnt[b];
      float avr = ssum[b + 4] / scnt[b + 4];
      float d = 0.1f * (avc - avr);                 // BETA = 0.1
      float ls = (d >= 0.f) ? -log1pf(__expf(-d)) : d - log1pf(__expf(d));
      pref += ls;
    }
    pref *= 0.25f;                                  // mean over 4 pairs
    out[0] = 1.0f * nll - pref;                     // ALPHA = 1.0
  }
}

extern "C" void kernel_launch(void* const* d_in, const int* in_sizes, int n_in,
                              void* d_out, int out_size, void* d_ws, size_t ws_size,
                              hipStream_t stream) {
  const float* lin_weight = (const float*)d_in[0];  // [V][H]
  const float* input      = (const float*)d_in[1];  // [B2][T][H]
  const int*   target     = (const int*)d_in[2];    // [B2][T]
  const float* bias       = (const float*)d_in[3];  // [V]
  float* out = (float*)d_out;

  uint8_t* ws = (uint8_t*)d_ws;
  size_t offW = 0;
  size_t offA = offW + (size_t)kV * kH * 2;            // 131,072,000 B
  size_t offP = offA + (size_t)kM * kH * 2;            // +33,554,432 B

  // pick the finest vocab split whose partials fit the workspace
  const int cand[3] = {125, 50, 25};
  int nsplit = 0;
  for (int ci = 0; ci < 3; ++ci) {
    size_t need = offP + (size_t)cand[ci] * kM * 16 + (size_t)kM * 4;
    if (need <= ws_size) { nsplit = cand[ci]; break; }
  }
  if (nsplit == 0) return;  // clean failure signal (output stays 0)
  int ntiles = kV / (nsplit * BN);
  size_t offT = offP + (size_t)nsplit * kM * 16;

  bf16_t* Wb = (bf16_t*)(ws + offW);
  bf16_t* Ab = (bf16_t*)(ws + offA);
  float4* partials = (float4*)(ws + offP);
  float*  per_tok  = (float*)(ws + offT);

  cast_to_bf16<<<2048, 256, 0, stream>>>(lin_weight, (uint2*)Wb, kV * kH / 4);
  cast_to_bf16<<<1024, 256, 0, stream>>>(input, (uint2*)Ab, kM * kH / 4);
  fused_lse<<<nsplit * MBLKS, 256, 0, stream>>>(Wb, Ab, bias, target, partials, ntiles);
  combine_lse<<<kM / 4, 256, 0, stream>>>(partials, per_tok, nsplit);
  final_loss<<<1, 1024, 0, stream>>>(per_tok, target, out);
}

// Round 5
// 1318.244 us; speedup vs baseline: 2.2826x; 1.2798x over previous
//
#include <hip/hip_runtime.h>
#include <hip/hip_bf16.h>
#include <stdint.h>

#define IGNORE_INDEX (-100)

constexpr int kB2 = 8, kT = 1024, kH = 2048, kV = 32000;
constexpr int kM = kB2 * kT;           // 8192 token rows
constexpr int BM = 128, BN = 256, BK = 64;
constexpr int NSPLIT = 25;             // vocab splits (divides 125 N-tiles)
constexpr int VSLICE = kV / NSPLIT;    // 1280 cols per split
constexpr int NT = VSLICE / BN;        // 5 N-tiles per block
constexpr int MBLKS = kM / BM;         // 64 row blocks
constexpr int KT = kH / BK;            // 32 K-tiles per N-tile
constexpr int SSTEPS = NT * KT;        // 160 pipelined steps per block
constexpr int NWG = NSPLIT * MBLKS;    // 1600 workgroups

typedef __bf16 bf16_t;
typedef __bf16 bf16x8 __attribute__((ext_vector_type(8)));
typedef float  f32x4  __attribute__((ext_vector_type(4)));

// ---------------- cast fp32 -> bf16 (vectorized) ----------------
__global__ void cast_to_bf16(const float* __restrict__ src, uint2* __restrict__ dst, int n4) {
  int idx = blockIdx.x * blockDim.x + threadIdx.x;
  int stride = gridDim.x * blockDim.x;
  const float4* s = (const float4*)src;
  for (int i = idx; i < n4; i += stride) {
    float4 v = s[i];
    union { bf16_t h[4]; uint2 u; } p;
    p.h[0] = (bf16_t)v.x; p.h[1] = (bf16_t)v.y;
    p.h[2] = (bf16_t)v.z; p.h[3] = (bf16_t)v.w;
    dst[i] = p.u;
  }
}

// async global->LDS, 16B per lane. LDS dest must be wave-uniform.
__device__ __forceinline__ void gload_lds16(const void* g, void* l) {
  __builtin_amdgcn_global_load_lds(
      (const __attribute__((address_space(1))) void*)g,
      (__attribute__((address_space(3))) void*)l, 16, 0, 0);
}

// ---------------- fused GEMM + online logsumexp + target grab ----------------
// Counted-vmcnt 3-buffer pipeline (T3+T4): per K-tile t:
//   STAGE(t+2 -> buf[(t+2)%3]); ds_read+MFMA tile t; [epilogue]; vmcnt(6); s_barrier.
// buf[(t+2)%3] == buf[(t-1)%3]: its reads finished before iter t-1's barrier.
// vmcnt(6) leaves only tile t+2's 6 loads in flight => tile t+1 landed; the
// barrier makes that true for ALL threads before anyone reads buf[(t+1)%3].
// LDS layout per buffer: A[128][64], B[256][64] bf16, chunk (row,j) holds
// global chunk (row, j ^ (row&7)) — pre-swizzled source, swizzled read (#21).
__global__ __launch_bounds__(512, 2) void fused_lse(
    const bf16_t* __restrict__ Wb,   // [V][H] bf16
    const bf16_t* __restrict__ Ab,   // [M][H] bf16
    const float* __restrict__ bias,  // [V]
    const int* __restrict__ target,  // [M]
    float4* __restrict__ partials)   // [NSPLIT][M] : (m, s, tgt_logit, 0)
{
  const int swz = (blockIdx.x & 7) * (NWG >> 3) + (blockIdx.x >> 3);  // bijective
  const int split = swz / MBLKS;
  const int mblk  = swz % MBLKS;
  const int tid  = threadIdx.x;
  const int lane = tid & 63;
  const int w    = tid >> 6;      // 0..7
  const int wm   = w >> 2;        // 0..1 : row half (64 rows)
  const int wn   = w & 3;         // 0..3 : col quarter (64 cols)
  const int g    = lane >> 4;
  const int li   = lane & 15;
  const int rowbase = mblk * BM;

  __shared__ __align__(16) uint8_t lds[3][48 * 1024];  // per buf: A 16KB | B 32KB

  f32x4 acc[4][4];                 // [m][n] frags of the wave's 64x64 tile
  float rM[4][4], rS[4][4], rT[4][4];
  int   tg[4][4];
  const f32x4 vzero = {0.f, 0.f, 0.f, 0.f};

#pragma unroll
  for (int m = 0; m < 4; ++m)
#pragma unroll
    for (int i = 0; i < 4; ++i) {
      rM[m][i] = -1e30f; rS[m][i] = 0.f; rT[m][i] = 0.f;
      int trow = rowbase + wm * 64 + m * 16 + g * 4 + i;
      int t = target[trow];
      tg[m][i] = (t == IGNORE_INDEX) ? 0 : t;
#pragma unroll
      for (int n = 0; n < 4; ++n) acc[m][n] = vzero;
    }

  // staging geometry: A = 16 segs of 1KB (wave w: segs 2w..2w+1),
  // B = 32 segs (wave w: segs 4w..4w+3). chunk c = seg*64+lane;
  // row=c>>3, col=c&7; global source col ^= row&7 (involution).
  int goffA[2], ldsoA[2], goffB[4], ldsoB[4];
#pragma unroll
  for (int it = 0; it < 2; ++it) {
    int seg = 2 * w + it, c = seg * 64 + lane;
    int row = c >> 3, col = c & 7;
    goffA[it] = row * (kH * 2) + ((col ^ (row & 7)) << 4);
    ldsoA[it] = seg * 1024;
  }
#pragma unroll
  for (int it = 0; it < 4; ++it) {
    int seg = 4 * w + it, c = seg * 64 + lane;
    int row = c >> 3, col = c & 7;
    goffB[it] = row * (kH * 2) + ((col ^ (row & 7)) << 4);
    ldsoB[it] = 16384 + seg * 1024;
  }

  const uint8_t* Agp = (const uint8_t*)(Ab + (size_t)rowbase * kH);
  const uint8_t* Wgp = (const uint8_t*)Wb + (size_t)split * VSLICE * (kH * 2);

  auto STAGE = [&](int s, int buf) {
    int nt = s >> 5, kb = (s & 31) << 7;   // K-byte offset = kt*64*2
    const uint8_t* Ag = Agp + kb;
    const uint8_t* Bg = Wgp + (size_t)nt * (BN * kH * 2) + kb;
    uint8_t* L = lds[buf];
#pragma unroll
    for (int it = 0; it < 2; ++it) gload_lds16(Ag + goffA[it], L + ldsoA[it]);
#pragma unroll
    for (int it = 0; it < 4; ++it) gload_lds16(Bg + goffB[it], L + ldsoB[it]);
  };

  // prologue: tiles 0,1 in flight; wait tile 0 (6 newest = tile 1 outstanding)
  STAGE(0, 0);
  STAGE(1, 1);
  asm volatile("s_waitcnt vmcnt(6)" ::: "memory");
  __builtin_amdgcn_s_barrier();

  for (int s = 0; s < SSTEPS; ++s) {
    const int bc = s % 3;
    if (s + 2 < SSTEPS) STAGE(s + 2, (s + 2) % 3);

    const uint8_t* As = lds[bc];
    const uint8_t* Bs = lds[bc] + 16384;
#pragma unroll
    for (int ks = 0; ks < 2; ++ks) {
      bf16x8 af[4], bf[4];
      int c16 = ks * 4 + g;
#pragma unroll
      for (int m = 0; m < 4; ++m) {
        int row = wm * 64 + m * 16 + li;
        af[m] = *(const bf16x8*)(As + row * 128 + ((c16 ^ (row & 7)) << 4));
      }
#pragma unroll
      for (int n = 0; n < 4; ++n) {
        int row = wn * 64 + n * 16 + li;
        bf[n] = *(const bf16x8*)(Bs + row * 128 + ((c16 ^ (row & 7)) << 4));
      }
#pragma unroll
      for (int m = 0; m < 4; ++m)
#pragma unroll
        for (int n = 0; n < 4; ++n)
          acc[m][n] = __builtin_amdgcn_mfma_f32_16x16x32_bf16(af[m], bf[n], acc[m][n], 0, 0, 0);
    }

    // ---- N-tile epilogue (registers/shfl only; overlaps in-flight loads) ----
    if ((s & 31) == 31) {
      int nt = s >> 5;
      int n0w = split * VSLICE + nt * BN + wn * 64;
      float bv[4];
#pragma unroll
      for (int n = 0; n < 4; ++n) bv[n] = bias[n0w + n * 16 + li];
#pragma unroll
      for (int m = 0; m < 4; ++m)
#pragma unroll
        for (int n = 0; n < 4; ++n)
#pragma unroll
          for (int i = 0; i < 4; ++i)
            acc[m][n][i] += bv[n];

#pragma unroll
      for (int m = 0; m < 4; ++m)
#pragma unroll
        for (int i = 0; i < 4; ++i) {
          float tmax = acc[m][0][i];
#pragma unroll
          for (int n = 1; n < 4; ++n) tmax = fmaxf(tmax, acc[m][n][i]);
#pragma unroll
          for (int d = 1; d <= 8; d <<= 1) tmax = fmaxf(tmax, __shfl_xor(tmax, d));
          float tsum = 0.f;
#pragma unroll
          for (int n = 0; n < 4; ++n) tsum += __expf(acc[m][n][i] - tmax);
#pragma unroll
          for (int d = 1; d <= 8; d <<= 1) tsum += __shfl_xor(tsum, d);
          float nm = fmaxf(rM[m][i], tmax);
          rS[m][i] = rS[m][i] * __expf(rM[m][i] - nm) + tsum * __expf(tmax - nm);
          rM[m][i] = nm;
          int c = tg[m][i] - n0w;   // wave-local col in [0,64)?
#pragma unroll
          for (int n = 0; n < 4; ++n)
            rT[m][i] += ((c >> 4) == n && (c & 15) == li) ? acc[m][n][i] : 0.f;
#pragma unroll
          for (int n = 0; n < 4; ++n) acc[m][n][i] = 0.f;
        }
    }

    if (s + 2 < SSTEPS)      asm volatile("s_waitcnt vmcnt(6)" ::: "memory");
    else if (s + 1 < SSTEPS) asm volatile("s_waitcnt vmcnt(0)" ::: "memory");
    __builtin_amdgcn_s_barrier();
  }

  // ---- reduce rT across 16-lane group, then merge wn partials via LDS ----
#pragma unroll
  for (int m = 0; m < 4; ++m)
#pragma unroll
    for (int i = 0; i < 4; ++i)
#pragma unroll
      for (int d = 1; d <= 8; d <<= 1) rT[m][i] += __shfl_xor(rT[m][i], d);

  // all vmem drained (vmcnt(0) at s==SSTEPS-2) and loop ended with a barrier:
  // LDS buffers are free to reuse.
  float4* mrg = (float4*)lds[0];   // [128 rows][4 wn]
  if (li == 0) {
#pragma unroll
    for (int m = 0; m < 4; ++m)
#pragma unroll
      for (int i = 0; i < 4; ++i) {
        int lr = wm * 64 + m * 16 + g * 4 + i;
        mrg[lr * 4 + wn] = float4{rM[m][i], rS[m][i], rT[m][i], 0.f};
      }
  }
  __syncthreads();
  if (tid < BM) {
    float mm = -1e30f, ss = 0.f, tt = 0.f;
#pragma unroll
    for (int q = 0; q < 4; ++q) {
      float4 p = mrg[tid * 4 + q];
      tt += p.z;
      float nm = fmaxf(mm, p.x);
      ss = ss * __expf(mm - nm) + p.y * __expf(p.x - nm);
      mm = nm;
    }
    partials[(size_t)split * kM + rowbase + tid] = float4{mm, ss, tt, 0.f};
  }
}

// ---------------- combine split partials -> per-token logp ----------------
// one wave per row; 64 lanes strided over splits, shfl LSE-merge.
// grid must be kM/4 blocks (4 waves per block, one row per wave).
__global__ __launch_bounds__(256) void combine_lse(
    const float4* __restrict__ partials, float* __restrict__ per_tok, int nsplit)
{
  int row  = blockIdx.x * 4 + (threadIdx.x >> 6);
  int lane = threadIdx.x & 63;
  float m = -1e30f, s = 0.f, t = 0.f;
  for (int sp = lane; sp < nsplit; sp += 64) {
    float4 p = partials[(size_t)sp * kM + row];
    t += p.z;
    float nm = fmaxf(m, p.x);
    s = s * __expf(m - nm) + p.y * __expf(p.x - nm);
    m = nm;
  }
#pragma unroll
  for (int d = 1; d < 64; d <<= 1) {
    float mo = __shfl_xor(m, d), so = __shfl_xor(s, d), to = __shfl_xor(t, d);
    float nm = fmaxf(m, mo);
    s = s * __expf(m - nm) + so * __expf(mo - nm);
    m = nm; t += to;
  }
  if (lane == 0) per_tok[row] = t - (m + logf(s));
}

// ---------------- final scalar loss ----------------
__global__ __launch_bounds__(1024) void final_loss(
    const float* __restrict__ per_tok, const int* __restrict__ target, float* __restrict__ out)
{
  __shared__ float redv[16], redc[16];
  __shared__ float ssum[8], scnt[8];
  int t = threadIdx.x;
  int wid = t >> 6, lane = t & 63;
  for (int b = 0; b < 8; ++b) {
    int row = b * 1024 + t;
    float mk = (target[row] != IGNORE_INDEX) ? 1.f : 0.f;
    float v = per_tok[row] * mk;
#pragma unroll
    for (int d = 1; d <= 32; d <<= 1) { v += __shfl_xor(v, d); mk += __shfl_xor(mk, d); }
    if (lane == 0) { redv[wid] = v; redc[wid] = mk; }
    __syncthreads();
    if (t == 0) {
      float sv = 0.f, sc = 0.f;
      for (int j = 0; j < 16; ++j) { sv += redv[j]; sc += redc[j]; }
      ssum[b] = sv; scnt[b] = sc;
    }
    __syncthreads();
  }
  if (t == 0) {
    float nsum = 0.f, ncnt = 0.f;
    for (int b = 0; b < 4; ++b) { nsum += ssum[b]; ncnt += scnt[b]; }
    float nll = -nsum / ncnt;
    float pref = 0.f;
    for (int b = 0; b < 4; ++b) {
      float avc = ssum[b] / scnt[b];
      float avr = ssum[b + 4] / scnt[b + 4];
      float d = 0.1f * (avc - avr);                 // BETA = 0.1
      float ls = (d >= 0.f) ? -log1pf(__expf(-d)) : d - log1pf(__expf(d));
      pref += ls;
    }
    pref *= 0.25f;                                  // mean over 4 pairs
    out[0] = 1.0f * nll - pref;                     // ALPHA = 1.0
  }
}

extern "C" void kernel_launch(void* const* d_in, const int* in_sizes, int n_in,
                              void* d_out, int out_size, void* d_ws, size_t ws_size,
                              hipStream_t stream) {
  const float* lin_weight = (const float*)d_in[0];  // [V][H]
  const float* input      = (const float*)d_in[1];  // [B2][T][H]
  const int*   target     = (const int*)d_in[2];    // [B2][T]
  const float* bias       = (const float*)d_in[3];  // [V]
  float* out = (float*)d_out;

  uint8_t* ws = (uint8_t*)d_ws;
  size_t offW = 0;
  size_t offA = offW + (size_t)kV * kH * 2;            // 131,072,000 B
  size_t offP = offA + (size_t)kM * kH * 2;            // +33,554,432 B
  size_t offT = offP + (size_t)NSPLIT * kM * 16;       // +3,276,800 B
  size_t need = offT + (size_t)kM * 4;
  if (ws_size < need) return;  // clean failure signal (output stays 0)

  bf16_t* Wb = (bf16_t*)(ws + offW);
  bf16_t* Ab = (bf16_t*)(ws + offA);
  float4* partials = (float4*)(ws + offP);
  float*  per_tok  = (float*)(ws + offT);

  cast_to_bf16<<<2048, 256, 0, stream>>>(lin_weight, (uint2*)Wb, kV * kH / 4);
  cast_to_bf16<<<1024, 256, 0, stream>>>(input, (uint2*)Ab, kM * kH / 4);
  fused_lse<<<NWG, 512, 0, stream>>>(Wb, Ab, bias, target, partials);
  combine_lse<<<kM / 4, 256, 0, stream>>>(partials, per_tok, NSPLIT);
  final_loss<<<1, 1024, 0, stream>>>(per_tok, target, out);
}

// Round 6
// 1078.045 us; speedup vs baseline: 2.7912x; 1.2228x over previous
//
#include <hip/hip_runtime.h>
#include <hip/hip_bf16.h>
#include <stdint.h>

#define IGNORE_INDEX (-100)

constexpr int kB2 = 8, kT = 1024, kH = 2048, kV = 32000;
constexpr int kM = kB2 * kT;           // 8192 token rows
constexpr int BM = 256, BN = 256, BK = 64;
constexpr int NSPLIT = 125;            // vocab splits (1 N-tile each)
constexpr int MBLKS = kM / BM;         // 32 row blocks
constexpr int KT = kH / BK;            // 32 K-tiles
constexpr int NWG = NSPLIT * MBLKS;    // 4000 workgroups

typedef __bf16 bf16_t;
typedef __bf16 bf16x8 __attribute__((ext_vector_type(8)));
typedef float  f32x4  __attribute__((ext_vector_type(4)));

// ---------------- cast fp32 -> bf16 (vectorized) ----------------
__global__ void cast_to_bf16(const float* __restrict__ src, uint2* __restrict__ dst, int n4) {
  int idx = blockIdx.x * blockDim.x + threadIdx.x;
  int stride = gridDim.x * blockDim.x;
  const float4* s = (const float4*)src;
  for (int i = idx; i < n4; i += stride) {
    float4 v = s[i];
    union { bf16_t h[4]; uint2 u; } p;
    p.h[0] = (bf16_t)v.x; p.h[1] = (bf16_t)v.y;
    p.h[2] = (bf16_t)v.z; p.h[3] = (bf16_t)v.w;
    dst[i] = p.u;
  }
}

__device__ __forceinline__ void gload_lds16(const void* g, void* l) {
  __builtin_amdgcn_global_load_lds(
      (const __attribute__((address_space(1))) void*)g,
      (__attribute__((address_space(3))) void*)l, 16, 0, 0);
}

// ---------------- fused GEMM + logsumexp + target grab ----------------
// 256x256x64 tile, 8 waves (4M x 2N; wave = 64 rows x 128 cols), 2 LDS dbuf.
// 4 phases per K-tile (m201-style): per phase {ds_read subtile; stage quarter
// of tile t+1 (A at ph0, B at ph1); s_barrier; setprio(1); 16 MFMA; setprio(0);
// s_barrier}. vmcnt(0) only at ph3 — prefetch loads fly across 3 barriers.
// LDS layout: linear [row][8 chunks of 16B]; chunk (row,j) holds global chunk
// (row, j^(row&7)) — pre-swizzled source, swizzled read (rule #21, involution).
// Block->(split,mblk) map: groups of 8 splits; within a group each XCD owns
// 4 A-panels and sweeps 8 splits per panel consecutively (A stays L2-resident;
// each W slice is read by exactly one XCD).
__global__ __launch_bounds__(512, 2) void fused_lse(
    const bf16_t* __restrict__ Wb,   // [V][H] bf16
    const bf16_t* __restrict__ Ab,   // [M][H] bf16
    const float* __restrict__ bias,  // [V]
    const int* __restrict__ target,  // [M]
    float4* __restrict__ partials)   // [NSPLIT][M] : (m, s, tgt_logit, 0)
{
  const int bid = blockIdx.x;
  const int gg = bid >> 8, r = bid & 255;
  int split, mblk;
  if (gg < 15) { int j = r >> 3; split = gg * 8 + (j & 7); mblk = (r & 7) * 4 + (j >> 3); }
  else         { split = 120 + (r >> 5); mblk = r & 31; }   // last group: 5 splits x 32

  const int tid = threadIdx.x;
  const int lane = tid & 63;
  const int w  = tid >> 6;     // 0..7
  const int wm = w >> 1;       // 0..3 : 64-row band
  const int wn = w & 1;        // 0..1 : 128-col half
  const int g  = lane >> 4;
  const int li = lane & 15;
  const int rowbase = mblk * BM;
  const int n0 = split * BN;

  __shared__ __align__(16) uint8_t lds[2][65536];   // per buf: A 32KB | B 32KB

  f32x4 acc[4][8];
  const f32x4 vzero = {0.f, 0.f, 0.f, 0.f};
#pragma unroll
  for (int m = 0; m < 4; ++m)
#pragma unroll
    for (int n = 0; n < 8; ++n) acc[m][n] = vzero;

  // staging geometry: A/B tiles are 32 segs of 1KB each; wave w owns segs
  // [4w,4w+4). chunk c = seg*64+lane; row=c>>3, col=c&7; source col ^= row&7.
  int goff[4], lofs[4];
#pragma unroll
  for (int it = 0; it < 4; ++it) {
    int seg = 4 * w + it, c = seg * 64 + lane;
    int row = c >> 3, col = c & 7;
    goff[it] = row * (kH * 2) + ((col ^ (row & 7)) << 4);
    lofs[it] = seg * 1024;
  }

  const uint8_t* Agp = (const uint8_t*)(Ab + (size_t)rowbase * kH);
  const uint8_t* Bgp = (const uint8_t*)(Wb + (size_t)n0 * kH);

  // prologue: stage tile 0 into buf 0
#pragma unroll
  for (int it = 0; it < 4; ++it) gload_lds16(Agp + goff[it], lds[0] + lofs[it]);
#pragma unroll
  for (int it = 0; it < 4; ++it) gload_lds16(Bgp + goff[it], lds[0] + 32768 + lofs[it]);
  asm volatile("s_waitcnt vmcnt(0)" ::: "memory");
  __builtin_amdgcn_s_barrier();

  for (int t = 0; t < KT; ++t) {
    const uint8_t* As = lds[t & 1];
    const uint8_t* Bs = lds[t & 1] + 32768;
    uint8_t* Ld = lds[(t + 1) & 1];
    const int kb = (t + 1) << 7;         // next tile's K byte offset
    const bool pf = (t + 1 < KT);        // workgroup-uniform
    bf16x8 af[4], bfv[4];

    // ---- phase 0: ks=0, B-quartet 0; stage A(t+1) ----
#pragma unroll
    for (int m = 0; m < 4; ++m) {
      int row = wm * 64 + m * 16 + li;
      af[m] = *(const bf16x8*)(As + row * 128 + ((g ^ (row & 7)) << 4));
    }
#pragma unroll
    for (int n = 0; n < 4; ++n) {
      int row = wn * 128 + n * 16 + li;
      bfv[n] = *(const bf16x8*)(Bs + row * 128 + ((g ^ (row & 7)) << 4));
    }
    if (pf) {
#pragma unroll
      for (int it = 0; it < 4; ++it) gload_lds16(Agp + goff[it] + kb, Ld + lofs[it]);
    }
    __builtin_amdgcn_s_barrier();
    __builtin_amdgcn_s_setprio(1);
#pragma unroll
    for (int m = 0; m < 4; ++m)
#pragma unroll
      for (int n = 0; n < 4; ++n)
        acc[m][n] = __builtin_amdgcn_mfma_f32_16x16x32_bf16(af[m], bfv[n], acc[m][n], 0, 0, 0);
    __builtin_amdgcn_s_setprio(0);
    __builtin_amdgcn_s_barrier();

    // ---- phase 1: ks=0, B-quartet 1; stage B(t+1) ----
#pragma unroll
    for (int n = 0; n < 4; ++n) {
      int row = wn * 128 + 64 + n * 16 + li;
      bfv[n] = *(const bf16x8*)(Bs + row * 128 + ((g ^ (row & 7)) << 4));
    }
    if (pf) {
#pragma unroll
      for (int it = 0; it < 4; ++it) gload_lds16(Bgp + goff[it] + kb, Ld + 32768 + lofs[it]);
    }
    __builtin_amdgcn_s_barrier();
    __builtin_amdgcn_s_setprio(1);
#pragma unroll
    for (int m = 0; m < 4; ++m)
#pragma unroll
      for (int n = 0; n < 4; ++n)
        acc[m][4 + n] = __builtin_amdgcn_mfma_f32_16x16x32_bf16(af[m], bfv[n], acc[m][4 + n], 0, 0, 0);
    __builtin_amdgcn_s_setprio(0);
    __builtin_amdgcn_s_barrier();

    // ---- phase 2: ks=1, B-quartet 0 ----
#pragma unroll
    for (int m = 0; m < 4; ++m) {
      int row = wm * 64 + m * 16 + li;
      af[m] = *(const bf16x8*)(As + row * 128 + (((4 + g) ^ (row & 7)) << 4));
    }
#pragma unroll
    for (int n = 0; n < 4; ++n) {
      int row = wn * 128 + n * 16 + li;
      bfv[n] = *(const bf16x8*)(Bs + row * 128 + (((4 + g) ^ (row & 7)) << 4));
    }
    __builtin_amdgcn_s_barrier();
    __builtin_amdgcn_s_setprio(1);
#pragma unroll
    for (int m = 0; m < 4; ++m)
#pragma unroll
      for (int n = 0; n < 4; ++n)
        acc[m][n] = __builtin_amdgcn_mfma_f32_16x16x32_bf16(af[m], bfv[n], acc[m][n], 0, 0, 0);
    __builtin_amdgcn_s_setprio(0);
    __builtin_amdgcn_s_barrier();

    // ---- phase 3: ks=1, B-quartet 1; drain tile t+1's loads ----
#pragma unroll
    for (int n = 0; n < 4; ++n) {
      int row = wn * 128 + 64 + n * 16 + li;
      bfv[n] = *(const bf16x8*)(Bs + row * 128 + (((4 + g) ^ (row & 7)) << 4));
    }
    __builtin_amdgcn_s_barrier();
    __builtin_amdgcn_s_setprio(1);
#pragma unroll
    for (int m = 0; m < 4; ++m)
#pragma unroll
      for (int n = 0; n < 4; ++n)
        acc[m][4 + n] = __builtin_amdgcn_mfma_f32_16x16x32_bf16(af[m], bfv[n], acc[m][4 + n], 0, 0, 0);
    __builtin_amdgcn_s_setprio(0);
    asm volatile("s_waitcnt vmcnt(0)" ::: "memory");  // t+1 landed (3 barriers of flight)
    __builtin_amdgcn_s_barrier();
  }

  // ---- epilogue (once per block): bias + LSE partial + target grab ----
  const int n0w = n0 + wn * 128;
  float bv[8];
#pragma unroll
  for (int n = 0; n < 8; ++n) bv[n] = bias[n0w + n * 16 + li];

  float4* mrg = (float4*)lds[0];   // [256 rows][2 wn] — K-loop fully drained
#pragma unroll
  for (int m = 0; m < 4; ++m)
#pragma unroll
    for (int i = 0; i < 4; ++i) {
#pragma unroll
      for (int n = 0; n < 8; ++n) acc[m][n][i] += bv[n];
      float tmax = acc[m][0][i];
#pragma unroll
      for (int n = 1; n < 8; ++n) tmax = fmaxf(tmax, acc[m][n][i]);
#pragma unroll
      for (int d = 1; d <= 8; d <<= 1) tmax = fmaxf(tmax, __shfl_xor(tmax, d));
      float tsum = 0.f;
#pragma unroll
      for (int n = 0; n < 8; ++n) tsum += __expf(acc[m][n][i] - tmax);
#pragma unroll
      for (int d = 1; d <= 8; d <<= 1) tsum += __shfl_xor(tsum, d);
      int trow = rowbase + wm * 64 + m * 16 + g * 4 + i;
      int tv = target[trow];
      int c = ((tv == IGNORE_INDEX) ? 0 : tv) - n0w;
      float rt = 0.f;
#pragma unroll
      for (int n = 0; n < 8; ++n)
        rt += ((c >> 4) == n && (c & 15) == li) ? acc[m][n][i] : 0.f;
#pragma unroll
      for (int d = 1; d <= 8; d <<= 1) rt += __shfl_xor(rt, d);
      if (li == 0) {
        int lr = wm * 64 + m * 16 + g * 4 + i;
        mrg[lr * 2 + wn] = float4{tmax, tsum, rt, 0.f};
      }
    }
  __syncthreads();
  if (tid < BM) {
    float4 p0 = mrg[tid * 2 + 0], p1 = mrg[tid * 2 + 1];
    float mm = fmaxf(p0.x, p1.x);
    float ss = p0.y * __expf(p0.x - mm) + p1.y * __expf(p1.x - mm);
    partials[(size_t)split * kM + rowbase + tid] = float4{mm, ss, p0.z + p1.z, 0.f};
  }
}

// ---------------- combine split partials -> per-token logp ----------------
// one wave per row; 64 lanes strided over splits, shfl LSE-merge. grid = kM/4.
__global__ __launch_bounds__(256) void combine_lse(
    const float4* __restrict__ partials, float* __restrict__ per_tok, int nsplit)
{
  int row  = blockIdx.x * 4 + (threadIdx.x >> 6);
  int lane = threadIdx.x & 63;
  float m = -1e30f, s = 0.f, t = 0.f;
  for (int sp = lane; sp < nsplit; sp += 64) {
    float4 p = partials[(size_t)sp * kM + row];
    t += p.z;
    float nm = fmaxf(m, p.x);
    s = s * __expf(m - nm) + p.y * __expf(p.x - nm);
    m = nm;
  }
#pragma unroll
  for (int d = 1; d < 64; d <<= 1) {
    float mo = __shfl_xor(m, d), so = __shfl_xor(s, d), to = __shfl_xor(t, d);
    float nm = fmaxf(m, mo);
    s = s * __expf(m - nm) + so * __expf(mo - nm);
    m = nm; t += to;
  }
  if (lane == 0) per_tok[row] = t - (m + logf(s));
}

// ---------------- final scalar loss ----------------
__global__ __launch_bounds__(1024) void final_loss(
    const float* __restrict__ per_tok, const int* __restrict__ target, float* __restrict__ out)
{
  __shared__ float redv[16], redc[16];
  __shared__ float ssum[8], scnt[8];
  int t = threadIdx.x;
  int wid = t >> 6, lane = t & 63;
  for (int b = 0; b < 8; ++b) {
    int row = b * 1024 + t;
    float mk = (target[row] != IGNORE_INDEX) ? 1.f : 0.f;
    float v = per_tok[row] * mk;
#pragma unroll
    for (int d = 1; d <= 32; d <<= 1) { v += __shfl_xor(v, d); mk += __shfl_xor(mk, d); }
    if (lane == 0) { redv[wid] = v; redc[wid] = mk; }
    __syncthreads();
    if (t == 0) {
      float sv = 0.f, sc = 0.f;
      for (int j = 0; j < 16; ++j) { sv += redv[j]; sc += redc[j]; }
      ssum[b] = sv; scnt[b] = sc;
    }
    __syncthreads();
  }
  if (t == 0) {
    float nsum = 0.f, ncnt = 0.f;
    for (int b = 0; b < 4; ++b) { nsum += ssum[b]; ncnt += scnt[b]; }
    float nll = -nsum / ncnt;
    float pref = 0.f;
    for (int b = 0; b < 4; ++b) {
      float avc = ssum[b] / scnt[b];
      float avr = ssum[b + 4] / scnt[b + 4];
      float d = 0.1f * (avc - avr);                 // BETA = 0.1
      float ls = (d >= 0.f) ? -log1pf(__expf(-d)) : d - log1pf(__expf(d));
      pref += ls;
    }
    pref *= 0.25f;                                  // mean over 4 pairs
    out[0] = 1.0f * nll - pref;                     // ALPHA = 1.0
  }
}

extern "C" void kernel_launch(void* const* d_in, const int* in_sizes, int n_in,
                              void* d_out, int out_size, void* d_ws, size_t ws_size,
                              hipStream_t stream) {
  const float* lin_weight = (const float*)d_in[0];  // [V][H]
  const float* input      = (const float*)d_in[1];  // [B2][T][H]
  const int*   target     = (const int*)d_in[2];    // [B2][T]
  const float* bias       = (const float*)d_in[3];  // [V]
  float* out = (float*)d_out;

  uint8_t* ws = (uint8_t*)d_ws;
  size_t offW = 0;
  size_t offA = offW + (size_t)kV * kH * 2;            // 131,072,000 B
  size_t offP = offA + (size_t)kM * kH * 2;            // +33,554,432 B
  size_t offT = offP + (size_t)NSPLIT * kM * 16;       // +16,384,000 B
  size_t need = offT + (size_t)kM * 4;
  if (ws_size < need) return;  // clean failure signal (output stays 0)
  // (round-4 ran nsplit=125 partials in this workspace: FETCH 4.24GB = 125 x A-panel)

  bf16_t* Wb = (bf16_t*)(ws + offW);
  bf16_t* Ab = (bf16_t*)(ws + offA);
  float4* partials = (float4*)(ws + offP);
  float*  per_tok  = (float*)(ws + offT);

  cast_to_bf16<<<2048, 256, 0, stream>>>(lin_weight, (uint2*)Wb, kV * kH / 4);
  cast_to_bf16<<<1024, 256, 0, stream>>>(input, (uint2*)Ab, kM * kH / 4);
  fused_lse<<<NWG, 512, 0, stream>>>(Wb, Ab, bias, target, partials);
  combine_lse<<<kM / 4, 256, 0, stream>>>(partials, per_tok, NSPLIT);
  final_loss<<<1, 1024, 0, stream>>>(per_tok, target, out);
}